// Round 8
// baseline (1086.587 us; speedup 1.0000x reference)
//
#include <hip/hip_runtime.h>
#include <hip/hip_cooperative_groups.h>

namespace coop = cooperative_groups;

static constexpr int B_ = 256;
static constexpr int R_ = 1152;
static constexpr int C_ = 10;
static constexpr int O_ = 16;
static constexpr int I_ = 8;
static constexpr int SCO = C_ * O_;   // 160
static constexpr int NV = B_ * SCO;   // 40960

// fused-kernel phase geometry
static constexpr int FSEG = 64, FRT = 18;   // phase S: 64 segs x 18 r, 512 items
static constexpr int ASEG = 128, ART = 9;   // phase A: 128 segs x 9 r, 512 items

// fallback (round-7) geometry
static constexpr int KS_NSEG = 128, KS_RT = 9;
static constexpr int KA_NSEG = 192, KA_RT = 6;

// ===========================================================================
// Persistent cooperative kernel: all 3 routing iterations, grid.sync between
// phases. Grid MUST be 512 blocks x 256 thr (co-resident at 2 blocks/CU).
// ===========================================================================
__global__ __launch_bounds__(256, 2) void k_fused(const float* __restrict__ x,
                                                  const float* __restrict__ W,
                                                  float* __restrict__ out,
                                                  float* __restrict__ partial,
                                                  float* __restrict__ v,
                                                  float* __restrict__ bvec,
                                                  float* __restrict__ cvec,
                                                  float* __restrict__ bpart) {
  __shared__ float smem[FRT * 8 * 68];        // 39.2 KB, reused per phase
  coop::grid_group grid = coop::this_grid();
  const int bx = blockIdx.x;
  const int t  = threadIdx.x;
  const int bl  = t & 15;
  const int grp = t >> 4;

  for (int it = 0; it < 3; ++it) {
    // ---------------- phase S: partial[seg][co][b] ----------------
    {
      const int seg = ((bx >> 6) << 3) | (bx & 7);   // 0..63, XCD-swizzled
      const int sub = (bx >> 3) & 7;
      const int bq = sub >> 1, ch = sub & 1;
      const int b0  = bq * 64 + bl * 4;
      const int co0 = ch * 80 + grp * 5;
      const int rbase = seg * FRT;
      // stage x[64b][18r][8i] -> smem[rr*8+i][b] (pad 68)
      for (int idx = t; idx < 64 * FRT * 2; idx += 256) {
        const int b = idx / (FRT * 2), f4 = idx - b * (FRT * 2);
        const float4 val = *(const float4*)(x + (size_t)(bq * 64 + b) * (R_ * I_)
                                              + rbase * I_ + f4 * 4);
        const int rr = f4 >> 1, i4 = (f4 & 1) * 4;
        smem[(rr * 8 + i4 + 0) * 68 + b] = val.x;
        smem[(rr * 8 + i4 + 1) * 68 + b] = val.y;
        smem[(rr * 8 + i4 + 2) * 68 + b] = val.z;
        smem[(rr * 8 + i4 + 3) * 68 + b] = val.w;
      }
      __syncthreads();

      const int cA = co0 >> 4, cB = (co0 + 4) >> 4;
      bool selB[5];
#pragma unroll
      for (int j = 0; j < 5; ++j) selB[j] = ((co0 + j) >> 4) != cA;

      float acc[4][5];
#pragma unroll
      for (int bb = 0; bb < 4; ++bb)
#pragma unroll
        for (int j = 0; j < 5; ++j) acc[bb][j] = 0.0f;

      for (int rr = 0; rr < FRT; ++rr) {
        const int r = rbase + rr;
        float4 wf[10];
        const float4* wp = (const float4*)(W + (size_t)r * 1280 + co0 * 8);
#pragma unroll
        for (int q = 0; q < 10; ++q) wf[q] = wp[q];
        const float cwA = (it > 0) ? cvec[r * C_ + cA] : (1.0f / 1152.0f);
        const float cwB = (it > 0) ? cvec[r * C_ + cB] : (1.0f / 1152.0f);
        float4 xv[8];
#pragma unroll
        for (int i = 0; i < 8; ++i)
          xv[i] = *(const float4*)(smem + (rr * 8 + i) * 68 + bl * 4);
        const float* xr = (const float*)xv;       // xr[i*4+bb]
#pragma unroll
        for (int j = 0; j < 5; ++j) {
          const float cw = selB[j] ? cwB : cwA;
          const float* wj = (const float*)&wf[j * 2];
#pragma unroll
          for (int bb = 0; bb < 4; ++bb) {
            float d = wj[0] * xr[bb];
            d = fmaf(wj[1], xr[4 + bb], d);  d = fmaf(wj[2], xr[8 + bb], d);
            d = fmaf(wj[3], xr[12 + bb], d); d = fmaf(wj[4], xr[16 + bb], d);
            d = fmaf(wj[5], xr[20 + bb], d); d = fmaf(wj[6], xr[24 + bb], d);
            d = fmaf(wj[7], xr[28 + bb], d);
            acc[bb][j] = fmaf(cw, d, acc[bb][j]);
          }
        }
      }
      float* pp = partial + (size_t)seg * NV + (size_t)co0 * 256 + b0;
#pragma unroll
      for (int j = 0; j < 5; ++j)
        *(float4*)(pp + j * 256) = make_float4(acc[0][j], acc[1][j], acc[2][j], acc[3][j]);
    }
    __threadfence();
    grid.sync();

    // ---------------- phase SV: squash ----------------
    {
      const int stride = (int)gridDim.x * 256;
      for (int i = bx * 256 + t; i < NV; i += stride) {
        float s = 0.0f;
#pragma unroll 8
        for (int g = 0; g < FSEG; ++g) s += partial[(size_t)g * NV + i];
        const float val = s * fabsf(s) / (1.0f + s * s);
        if (it == 2) out[(i & 255) * SCO + (i >> 8)] = val;  // out[b][co]
        else         v[i] = val;                             // v[co][b]
      }
    }
    if (it == 2) return;
    __threadfence();
    grid.sync();

    // ---------------- phase A: bpart[bq][r][c] ----------------
    {
      const int seg = ((bx >> 5) << 3) | (bx & 7);   // 0..127
      const int bq  = (bx >> 3) & 3;
      const int b0 = bq * 64 + bl * 4;
      const int rbase = seg * ART;
      float* sx  = smem;                  // 4896 floats
      float* red = smem + ART * 8 * 68;   // 1440 floats [rr][grp][c]

      for (int idx = t; idx < 64 * ART * 2; idx += 256) {
        const int b = idx / (ART * 2), f4 = idx - b * (ART * 2);
        const float4 val = *(const float4*)(x + (size_t)(bq * 64 + b) * (R_ * I_)
                                              + rbase * I_ + f4 * 4);
        const int rr = f4 >> 1, i4 = (f4 & 1) * 4;
        sx[(rr * 8 + i4 + 0) * 68 + b] = val.x;
        sx[(rr * 8 + i4 + 1) * 68 + b] = val.y;
        sx[(rr * 8 + i4 + 2) * 68 + b] = val.z;
        sx[(rr * 8 + i4 + 3) * 68 + b] = val.w;
      }
      float4 vf[10];                      // v[c=j][o=grp][b0..3]
#pragma unroll
      for (int j = 0; j < 10; ++j)
        vf[j] = *(const float4*)(v + (size_t)(j * 16 + grp) * 256 + b0);
      __syncthreads();

      for (int rr = 0; rr < ART; ++rr) {
        const int r = rbase + rr;
        float4 xv[8];
#pragma unroll
        for (int i = 0; i < 8; ++i)
          xv[i] = *(const float4*)(sx + (rr * 8 + i) * 68 + bl * 4);
        const float* xr = (const float*)xv;
        float p[10];
#pragma unroll
        for (int j = 0; j < 10; ++j) {
          const float* wj = W + (size_t)((r * C_ + j) * O_ + grp) * I_;
          const float4 w0 = *(const float4*)wj, w1 = *(const float4*)(wj + 4);
          const float* vfj = (const float*)&vf[j];
          float a = 0.0f;
#pragma unroll
          for (int bb = 0; bb < 4; ++bb) {
            float d = w0.x * xr[bb];
            d = fmaf(w0.y, xr[4 + bb], d);  d = fmaf(w0.z, xr[8 + bb], d);
            d = fmaf(w0.w, xr[12 + bb], d); d = fmaf(w1.x, xr[16 + bb], d);
            d = fmaf(w1.y, xr[20 + bb], d); d = fmaf(w1.z, xr[24 + bb], d);
            d = fmaf(w1.w, xr[28 + bb], d);
            a = fmaf(d, vfj[bb], a);
          }
          p[j] = a;
        }
#pragma unroll
        for (int j = 0; j < 10; ++j) {
          float a = p[j];
          a += __shfl_xor(a, 1); a += __shfl_xor(a, 2);
          a += __shfl_xor(a, 4); a += __shfl_xor(a, 8);
          p[j] = a;
        }
        if (bl == 0) {
#pragma unroll
          for (int j = 0; j < 10; ++j) red[(rr * 16 + grp) * 10 + j] = p[j];
        }
      }
      __syncthreads();
      if (t < ART * 10) {
        const int rr = t / 10, c = t - rr * 10;
        float s = 0.0f;
#pragma unroll
        for (int g = 0; g < 16; ++g) s += red[(rr * 16 + g) * 10 + c];
        bpart[((size_t)bq * R_ + (rbase + rr)) * C_ + c] = s;
      }
    }
    __threadfence();
    grid.sync();

    // ---------------- phase BC: logits + softmax ----------------
    if (bx < C_) {
      const int c = bx;
      float* smx = smem;
      float* sms = smem + 4;
      float bv[5], ef[5];
      float mx = -3.402823466e38f;
#pragma unroll
      for (int k = 0; k < 5; ++k) {
        int r = t + k * 256;
        if (r < R_) {
          float s = bpart[(size_t)r * C_ + c]
                  + bpart[((size_t)R_ + r) * C_ + c]
                  + bpart[((size_t)2 * R_ + r) * C_ + c]
                  + bpart[((size_t)3 * R_ + r) * C_ + c];
          float val = s * (1.0f / 256.0f);
          if (it != 0) val += bvec[r * C_ + c];
          bvec[r * C_ + c] = val;
          bv[k] = val;
          mx = fmaxf(mx, val);
        }
      }
      mx = fmaxf(mx, __shfl_xor(mx, 1));  mx = fmaxf(mx, __shfl_xor(mx, 2));
      mx = fmaxf(mx, __shfl_xor(mx, 4));  mx = fmaxf(mx, __shfl_xor(mx, 8));
      mx = fmaxf(mx, __shfl_xor(mx, 16)); mx = fmaxf(mx, __shfl_xor(mx, 32));
      if ((t & 63) == 0) smx[t >> 6] = mx;
      __syncthreads();
      const float MX = fmaxf(fmaxf(smx[0], smx[1]), fmaxf(smx[2], smx[3]));
      float se = 0.0f;
#pragma unroll
      for (int k = 0; k < 5; ++k) {
        int r = t + k * 256;
        if (r < R_) { ef[k] = expf(bv[k] - MX); se += ef[k]; }
      }
      se += __shfl_xor(se, 1);  se += __shfl_xor(se, 2);  se += __shfl_xor(se, 4);
      se += __shfl_xor(se, 8);  se += __shfl_xor(se, 16); se += __shfl_xor(se, 32);
      if ((t & 63) == 0) sms[t >> 6] = se;
      __syncthreads();
      const float inv = 1.0f / ((sms[0] + sms[1]) + (sms[2] + sms[3]));
#pragma unroll
      for (int k = 0; k < 5; ++k) {
        int r = t + k * 256;
        if (r < R_) cvec[r * C_ + c] = ef[k] * inv;
      }
    }
    __threadfence();
    grid.sync();
  }
}

// ===========================================================================
// Fallback path: round-7 kernels, verbatim (used only if coop launch fails).
// ===========================================================================
__global__ __launch_bounds__(256, 4) void k_s(const float* __restrict__ x,
                                              const float* __restrict__ W,
                                              const float* __restrict__ cvec,
                                              float* __restrict__ partial,
                                              int use_c) {
  __shared__ float sx[KS_RT * 8 * 68];
  const int bx  = blockIdx.x;
  const int seg = ((bx >> 6) << 3) | (bx & 7);
  const int sub = (bx >> 3) & 7;
  const int bq = sub >> 1;
  const int ch = sub & 1;
  const int t  = threadIdx.x;
  const int bl  = t & 15;
  const int grp = t >> 4;
  const int b0  = bq * 64 + bl * 4;
  const int co0 = ch * 80 + grp * 5;
  const int rbase = seg * KS_RT;
  for (int idx = t; idx < 64 * KS_RT * 2; idx += 256) {
    const int b = idx / (KS_RT * 2), f4 = idx - b * (KS_RT * 2);
    const float4 val = *(const float4*)(x + (size_t)(bq * 64 + b) * (R_ * I_)
                                          + rbase * I_ + f4 * 4);
    const int rr = f4 >> 1, i4 = (f4 & 1) * 4;
    sx[(rr * 8 + i4 + 0) * 68 + b] = val.x;
    sx[(rr * 8 + i4 + 1) * 68 + b] = val.y;
    sx[(rr * 8 + i4 + 2) * 68 + b] = val.z;
    sx[(rr * 8 + i4 + 3) * 68 + b] = val.w;
  }
  __syncthreads();
  const int cA = co0 >> 4, cB = (co0 + 4) >> 4;
  bool selB[5];
#pragma unroll
  for (int j = 0; j < 5; ++j) selB[j] = ((co0 + j) >> 4) != cA;
  float acc[4][5];
#pragma unroll
  for (int bb = 0; bb < 4; ++bb)
#pragma unroll
    for (int j = 0; j < 5; ++j) acc[bb][j] = 0.0f;
  for (int rr = 0; rr < KS_RT; ++rr) {
    const int r = rbase + rr;
    float4 wf[10];
    const float4* wp = (const float4*)(W + (size_t)r * 1280 + co0 * 8);
#pragma unroll
    for (int q = 0; q < 10; ++q) wf[q] = wp[q];
    const float cwA = use_c ? cvec[r * C_ + cA] : (1.0f / 1152.0f);
    const float cwB = use_c ? cvec[r * C_ + cB] : (1.0f / 1152.0f);
    float4 xv[8];
#pragma unroll
    for (int i = 0; i < 8; ++i)
      xv[i] = *(const float4*)(sx + (rr * 8 + i) * 68 + bl * 4);
    const float* xr = (const float*)xv;
#pragma unroll
    for (int j = 0; j < 5; ++j) {
      const float cw = selB[j] ? cwB : cwA;
      const float* wj = (const float*)&wf[j * 2];
#pragma unroll
      for (int bb = 0; bb < 4; ++bb) {
        float d = wj[0] * xr[bb];
        d = fmaf(wj[1], xr[4 + bb], d);  d = fmaf(wj[2], xr[8 + bb], d);
        d = fmaf(wj[3], xr[12 + bb], d); d = fmaf(wj[4], xr[16 + bb], d);
        d = fmaf(wj[5], xr[20 + bb], d); d = fmaf(wj[6], xr[24 + bb], d);
        d = fmaf(wj[7], xr[28 + bb], d);
        acc[bb][j] = fmaf(cw, d, acc[bb][j]);
      }
    }
  }
  float* pp = partial + (size_t)seg * NV + (size_t)co0 * 256 + b0;
#pragma unroll
  for (int j = 0; j < 5; ++j)
    *(float4*)(pp + j * 256) = make_float4(acc[0][j], acc[1][j], acc[2][j], acc[3][j]);
}

__global__ __launch_bounds__(256) void k_sv(const float* __restrict__ partial,
                                            float* __restrict__ dst, int direct) {
  const int i = blockIdx.x * 256 + threadIdx.x;
  float s = 0.0f;
#pragma unroll 8
  for (int g = 0; g < KS_NSEG; ++g) s += partial[(size_t)g * NV + i];
  const float val = s * fabsf(s) / (1.0f + s * s);
  if (direct) dst[(i & 255) * SCO + (i >> 8)] = val;
  else        dst[i] = val;
}

__global__ __launch_bounds__(256, 3) void k_a(const float* __restrict__ x,
                                              const float* __restrict__ W,
                                              const float* __restrict__ v,
                                              float* __restrict__ bpart) {
  __shared__ float sx[KA_RT * 8 * 68];
  __shared__ float red[KA_RT][16][10];
  const int bx  = blockIdx.x;
  const int seg = ((bx >> 5) << 3) | (bx & 7);
  const int bq  = (bx >> 3) & 3;
  const int t   = threadIdx.x;
  const int bl  = t & 15;
  const int grp = t >> 4;
  const int b0  = bq * 64 + bl * 4;
  const int rbase = seg * KA_RT;
  for (int idx = t; idx < 64 * KA_RT * 2; idx += 256) {
    const int b = idx / (KA_RT * 2), f4 = idx - b * (KA_RT * 2);
    const float4 val = *(const float4*)(x + (size_t)(bq * 64 + b) * (R_ * I_)
                                          + rbase * I_ + f4 * 4);
    const int rr = f4 >> 1, i4 = (f4 & 1) * 4;
    sx[(rr * 8 + i4 + 0) * 68 + b] = val.x;
    sx[(rr * 8 + i4 + 1) * 68 + b] = val.y;
    sx[(rr * 8 + i4 + 2) * 68 + b] = val.z;
    sx[(rr * 8 + i4 + 3) * 68 + b] = val.w;
  }
  float4 vf[10];
#pragma unroll
  for (int j = 0; j < 10; ++j)
    vf[j] = *(const float4*)(v + (size_t)(j * 16 + grp) * 256 + b0);
  __syncthreads();
  for (int rr = 0; rr < KA_RT; ++rr) {
    const int r = rbase + rr;
    float4 xv[8];
#pragma unroll
    for (int i = 0; i < 8; ++i)
      xv[i] = *(const float4*)(sx + (rr * 8 + i) * 68 + bl * 4);
    const float* xr = (const float*)xv;
    float p[10];
#pragma unroll
    for (int j = 0; j < 10; ++j) {
      const float* wj = W + (size_t)((r * C_ + j) * O_ + grp) * I_;
      const float4 w0 = *(const float4*)wj, w1 = *(const float4*)(wj + 4);
      const float* vfj = (const float*)&vf[j];
      float a = 0.0f;
#pragma unroll
      for (int bb = 0; bb < 4; ++bb) {
        float d = w0.x * xr[bb];
        d = fmaf(w0.y, xr[4 + bb], d);  d = fmaf(w0.z, xr[8 + bb], d);
        d = fmaf(w0.w, xr[12 + bb], d); d = fmaf(w1.x, xr[16 + bb], d);
        d = fmaf(w1.y, xr[20 + bb], d); d = fmaf(w1.z, xr[24 + bb], d);
        d = fmaf(w1.w, xr[28 + bb], d);
        a = fmaf(d, vfj[bb], a);
      }
      p[j] = a;
    }
#pragma unroll
    for (int j = 0; j < 10; ++j) {
      float a = p[j];
      a += __shfl_xor(a, 1); a += __shfl_xor(a, 2);
      a += __shfl_xor(a, 4); a += __shfl_xor(a, 8);
      p[j] = a;
    }
    if (bl == 0) {
#pragma unroll
      for (int j = 0; j < 10; ++j) red[rr][grp][j] = p[j];
    }
  }
  __syncthreads();
  if (t < KA_RT * 10) {
    const int rr = t / 10, c = t - rr * 10;
    float s = 0.0f;
#pragma unroll
    for (int g = 0; g < 16; ++g) s += red[rr][g][c];
    bpart[((size_t)bq * R_ + (rbase + rr)) * C_ + c] = s;
  }
}

__global__ __launch_bounds__(256) void k_bc(const float* __restrict__ bpart,
                                            float* __restrict__ bvec,
                                            float* __restrict__ cvec, int first) {
  const int c = blockIdx.x;
  const int t = threadIdx.x;
  __shared__ float smx[4];
  __shared__ float sms[4];
  float bv[5], ef[5];
  float mx = -3.402823466e38f;
#pragma unroll
  for (int k = 0; k < 5; ++k) {
    int r = t + k * 256;
    if (r < R_) {
      float s = bpart[(size_t)r * C_ + c]
              + bpart[((size_t)R_ + r) * C_ + c]
              + bpart[((size_t)2 * R_ + r) * C_ + c]
              + bpart[((size_t)3 * R_ + r) * C_ + c];
      float val = s * (1.0f / 256.0f);
      if (!first) val += bvec[r * C_ + c];
      bvec[r * C_ + c] = val;
      bv[k] = val;
      mx = fmaxf(mx, val);
    }
  }
  mx = fmaxf(mx, __shfl_xor(mx, 1));  mx = fmaxf(mx, __shfl_xor(mx, 2));
  mx = fmaxf(mx, __shfl_xor(mx, 4));  mx = fmaxf(mx, __shfl_xor(mx, 8));
  mx = fmaxf(mx, __shfl_xor(mx, 16)); mx = fmaxf(mx, __shfl_xor(mx, 32));
  if ((t & 63) == 0) smx[t >> 6] = mx;
  __syncthreads();
  const float MX = fmaxf(fmaxf(smx[0], smx[1]), fmaxf(smx[2], smx[3]));
  float se = 0.0f;
#pragma unroll
  for (int k = 0; k < 5; ++k) {
    int r = t + k * 256;
    if (r < R_) { ef[k] = expf(bv[k] - MX); se += ef[k]; }
  }
  se += __shfl_xor(se, 1);  se += __shfl_xor(se, 2);  se += __shfl_xor(se, 4);
  se += __shfl_xor(se, 8);  se += __shfl_xor(se, 16); se += __shfl_xor(se, 32);
  if ((t & 63) == 0) sms[t >> 6] = se;
  __syncthreads();
  const float inv = 1.0f / ((sms[0] + sms[1]) + (sms[2] + sms[3]));
#pragma unroll
  for (int k = 0; k < 5; ++k) {
    int r = t + k * 256;
    if (r < R_) cvec[r * C_ + c] = ef[k] * inv;
  }
}

extern "C" void kernel_launch(void* const* d_in, const int* in_sizes, int n_in,
                              void* d_out, int out_size, void* d_ws, size_t ws_size,
                              hipStream_t stream) {
  const float* x = (const float*)d_in[0];  // (B,R,I) fp32
  const float* W = (const float*)d_in[1];  // (R,C,O,I) fp32
  float* out = (float*)d_out;              // (B,C,O,1) fp32
  float* ws = (float*)d_ws;

  float* partial = ws;                             // 128*NV (covers both paths)
  float* v     = partial + (size_t)KS_NSEG * NV;
  float* bvec  = v + NV;
  float* cvec  = bvec + (R_ * C_);
  float* bpart = cvec + (R_ * C_);

  void* args[] = {(void*)&x, (void*)&W, (void*)&out, (void*)&partial,
                  (void*)&v, (void*)&bvec, (void*)&cvec, (void*)&bpart};
  hipError_t err = hipLaunchCooperativeKernel((void*)k_fused, dim3(512), dim3(256),
                                              args, 0, stream);
  if (err != hipSuccess) {
    // fallback: known-good round-7 multi-dispatch pipeline
    for (int it = 0; it < 3; ++it) {
      k_s<<<KS_NSEG * 8, 256, 0, stream>>>(x, W, cvec, partial, it > 0 ? 1 : 0);
      k_sv<<<NV / 256, 256, 0, stream>>>(partial, (it == 2) ? out : v, it == 2 ? 1 : 0);
      if (it < 2) {
        k_a<<<KA_NSEG * 4, 256, 0, stream>>>(x, W, v, bpart);
        k_bc<<<C_, 256, 0, stream>>>(bpart, bvec, cvec, it == 0 ? 1 : 0);
      }
    }
  }
}

// Round 9
// 256.463 us; speedup vs baseline: 4.2368x; 4.2368x over previous
//
#include <hip/hip_runtime.h>

static constexpr int B_ = 256;
static constexpr int R_ = 1152;
static constexpr int C_ = 10;
static constexpr int O_ = 16;
static constexpr int I_ = 8;
static constexpr int SCO = C_ * O_;   // 160
static constexpr int NV = B_ * SCO;   // 40960

static constexpr int KS_NSEG = 128, KS_RT = 9;   // k_s: 128 segs x 9 r
static constexpr int KA_NSEG = 192, KA_RT = 6;   // k_a: 192 segs x 6 r

// ---------------------------------------------------------------------------
// k_s: partial[seg][co][b] = sum_{r in seg} c[r,c(co)] * (W[r,co,:] . x[b,r,:])
// Block = (seg, bq): 64 b x 160 co x 9 r. Thread: bl=t&7 -> 8 b's,
// grp=t>>3 -> 5 co's. 8-b tile halves W-load instrs per FMA vs 4-b tile.
// x staged coalesced -> LDS [r][i][b pad68]. grid = 128*4 = 512, XCD-swizzled.
// ---------------------------------------------------------------------------
__global__ __launch_bounds__(256, 2) void k_s(const float* __restrict__ x,
                                              const float* __restrict__ W,
                                              const float* __restrict__ cvec,
                                              float* __restrict__ partial,
                                              int use_c) {
  __shared__ float sx[KS_RT * 8 * 68];           // 19.6 KB
  const int bx  = blockIdx.x;
  const int seg = ((bx >> 5) << 3) | (bx & 7);   // 0..127, same-seg -> same XCD
  const int bq  = (bx >> 3) & 3;
  const int t   = threadIdx.x;
  const int bl  = t & 7;                         // b-octet
  const int grp = t >> 3;                        // 0..31
  const int b0  = bq * 64 + bl * 8;
  const int co0 = grp * 5;
  const int rbase = seg * KS_RT;

  // stage x[64b][9r][8i] -> sx[rr*8+i][b]
  for (int idx = t; idx < 64 * KS_RT * 2; idx += 256) {
    const int b = idx / (KS_RT * 2), f4 = idx - b * (KS_RT * 2);
    const float4 val = *(const float4*)(x + (size_t)(bq * 64 + b) * (R_ * I_)
                                          + rbase * I_ + f4 * 4);
    const int rr = f4 >> 1, i4 = (f4 & 1) * 4;
    sx[(rr * 8 + i4 + 0) * 68 + b] = val.x;
    sx[(rr * 8 + i4 + 1) * 68 + b] = val.y;
    sx[(rr * 8 + i4 + 2) * 68 + b] = val.z;
    sx[(rr * 8 + i4 + 3) * 68 + b] = val.w;
  }
  __syncthreads();

  const int cA = co0 >> 4, cB = (co0 + 4) >> 4;
  bool selB[5];
#pragma unroll
  for (int j = 0; j < 5; ++j) selB[j] = ((co0 + j) >> 4) != cA;

  float acc[5][8];
#pragma unroll
  for (int j = 0; j < 5; ++j)
#pragma unroll
    for (int bb = 0; bb < 8; ++bb) acc[j][bb] = 0.0f;

#pragma unroll 3
  for (int rr = 0; rr < KS_RT; ++rr) {
    const int r = rbase + rr;
    float4 wf[10];
    const float4* wp = (const float4*)(W + (size_t)r * 1280 + co0 * 8);
#pragma unroll
    for (int q = 0; q < 10; ++q) wf[q] = wp[q];
    const float cwA = use_c ? cvec[r * C_ + cA] : (1.0f / 1152.0f);
    const float cwB = use_c ? cvec[r * C_ + cB] : (1.0f / 1152.0f);
    float xr[8][8];                              // [i][bb]
#pragma unroll
    for (int i = 0; i < 8; ++i) {
      const float4 A = *(const float4*)(sx + (rr * 8 + i) * 68 + bl * 8);
      const float4 Bv = *(const float4*)(sx + (rr * 8 + i) * 68 + bl * 8 + 4);
      xr[i][0] = A.x;  xr[i][1] = A.y;  xr[i][2] = A.z;  xr[i][3] = A.w;
      xr[i][4] = Bv.x; xr[i][5] = Bv.y; xr[i][6] = Bv.z; xr[i][7] = Bv.w;
    }
#pragma unroll
    for (int j = 0; j < 5; ++j) {
      const float cw = selB[j] ? cwB : cwA;
      const float* wj = (const float*)&wf[j * 2];
#pragma unroll
      for (int bb = 0; bb < 8; ++bb) {
        float d = wj[0] * xr[0][bb];
        d = fmaf(wj[1], xr[1][bb], d); d = fmaf(wj[2], xr[2][bb], d);
        d = fmaf(wj[3], xr[3][bb], d); d = fmaf(wj[4], xr[4][bb], d);
        d = fmaf(wj[5], xr[5][bb], d); d = fmaf(wj[6], xr[6][bb], d);
        d = fmaf(wj[7], xr[7][bb], d);
        acc[j][bb] = fmaf(cw, d, acc[j][bb]);
      }
    }
  }
  float* base = partial + (size_t)seg * NV + b0;
#pragma unroll
  for (int j = 0; j < 5; ++j) {
    *(float4*)(base + (co0 + j) * 256)     = make_float4(acc[j][0], acc[j][1], acc[j][2], acc[j][3]);
    *(float4*)(base + (co0 + j) * 256 + 4) = make_float4(acc[j][4], acc[j][5], acc[j][6], acc[j][7]);
  }
}

// s = sum over partials; squash v = s*|s|/(1+s^2)
// (== s^3/((1+s^2)*sqrt(s^2)) for s != 0; division-safe everywhere)
// v layout [co][b]; final pass (direct=1) scatter-transposes to out[b][co].
__global__ __launch_bounds__(256) void k_sv(const float* __restrict__ partial,
                                            float* __restrict__ dst, int direct) {
  const int i = blockIdx.x * 256 + threadIdx.x;  // i = co*256 + b
  float s = 0.0f;
#pragma unroll 8
  for (int g = 0; g < KS_NSEG; ++g) s += partial[(size_t)g * NV + i];
  const float val = s * fabsf(s) / (1.0f + s * s);
  if (direct) dst[(i & 255) * SCO + (i >> 8)] = val;
  else        dst[i] = val;
}

// ---------------------------------------------------------------------------
// k_a: bpart[bq][r][c] = sum_{b in bq} sum_o (W[r,c,o,:].x[b,r,:]) * v[b,c,o]
// Block = (seg of 6 r, bq). Thread: bl=t&7 -> 8 b's; grp=t>>3: o=grp&15,
// ch=grp>>4 -> 5 c's. b-reduce = 3 shfl; o/wave-reduce via LDS red.
// grid = 192*4 = 768, XCD-swizzled on seg.
// ---------------------------------------------------------------------------
__global__ __launch_bounds__(256, 3) void k_a(const float* __restrict__ x,
                                              const float* __restrict__ W,
                                              const float* __restrict__ v,
                                              float* __restrict__ bpart) {
  __shared__ float sx[KA_RT * 8 * 68];           // 13 KB
  __shared__ float red[KA_RT * 32 * 5];          // 3.75 KB, [rr][grp][cc]
  const int bx  = blockIdx.x;
  const int seg = ((bx >> 5) << 3) | (bx & 7);   // 0..191
  const int bq  = (bx >> 3) & 3;
  const int t   = threadIdx.x;
  const int bl  = t & 7;
  const int grp = t >> 3;                        // 0..31
  const int o   = grp & 15;
  const int ch  = grp >> 4;                      // c-half
  const int c0  = ch * 5;
  const int b0  = bq * 64 + bl * 8;
  const int rbase = seg * KA_RT;

  for (int idx = t; idx < 64 * KA_RT * 2; idx += 256) {
    const int b = idx / (KA_RT * 2), f4 = idx - b * (KA_RT * 2);
    const float4 val = *(const float4*)(x + (size_t)(bq * 64 + b) * (R_ * I_)
                                          + rbase * I_ + f4 * 4);
    const int rr = f4 >> 1, i4 = (f4 & 1) * 4;
    sx[(rr * 8 + i4 + 0) * 68 + b] = val.x;
    sx[(rr * 8 + i4 + 1) * 68 + b] = val.y;
    sx[(rr * 8 + i4 + 2) * 68 + b] = val.z;
    sx[(rr * 8 + i4 + 3) * 68 + b] = val.w;
  }

  float vf[5][8];                                // v[c0+j][o][b0..b0+7]
#pragma unroll
  for (int j = 0; j < 5; ++j) {
    const float* vb = v + (size_t)((c0 + j) * 16 + o) * 256 + b0;
    const float4 A = *(const float4*)vb, Bv = *(const float4*)(vb + 4);
    vf[j][0] = A.x;  vf[j][1] = A.y;  vf[j][2] = A.z;  vf[j][3] = A.w;
    vf[j][4] = Bv.x; vf[j][5] = Bv.y; vf[j][6] = Bv.z; vf[j][7] = Bv.w;
  }
  __syncthreads();

#pragma unroll 3
  for (int rr = 0; rr < KA_RT; ++rr) {
    const int r = rbase + rr;
    float xr[8][8];
#pragma unroll
    for (int i = 0; i < 8; ++i) {
      const float4 A = *(const float4*)(sx + (rr * 8 + i) * 68 + bl * 8);
      const float4 Bv = *(const float4*)(sx + (rr * 8 + i) * 68 + bl * 8 + 4);
      xr[i][0] = A.x;  xr[i][1] = A.y;  xr[i][2] = A.z;  xr[i][3] = A.w;
      xr[i][4] = Bv.x; xr[i][5] = Bv.y; xr[i][6] = Bv.z; xr[i][7] = Bv.w;
    }
#pragma unroll
    for (int j = 0; j < 5; ++j) {
      const float* wj = W + (size_t)((r * C_ + c0 + j) * O_ + o) * I_;
      const float4 w0 = *(const float4*)wj, w1 = *(const float4*)(wj + 4);
      const float wa[8] = {w0.x, w0.y, w0.z, w0.w, w1.x, w1.y, w1.z, w1.w};
      float a = 0.0f;
#pragma unroll
      for (int bb = 0; bb < 8; ++bb) {
        float d = wa[0] * xr[0][bb];
        d = fmaf(wa[1], xr[1][bb], d); d = fmaf(wa[2], xr[2][bb], d);
        d = fmaf(wa[3], xr[3][bb], d); d = fmaf(wa[4], xr[4][bb], d);
        d = fmaf(wa[5], xr[5][bb], d); d = fmaf(wa[6], xr[6][bb], d);
        d = fmaf(wa[7], xr[7][bb], d);
        a = fmaf(d, vf[j][bb], a);
      }
      // reduce over the 8 b-lanes (bl = t&7, in-wave)
      a += __shfl_xor(a, 1); a += __shfl_xor(a, 2); a += __shfl_xor(a, 4);
      if (bl == 0) red[(rr * 32 + grp) * 5 + j] = a;
    }
  }
  __syncthreads();
  if (t < KA_RT * 10) {
    const int rr = t / 10, c = t - rr * 10;
    const int ch2 = c / 5, cc = c - ch2 * 5;
    float s = 0.0f;
#pragma unroll
    for (int o2 = 0; o2 < 16; ++o2)
      s += red[(rr * 32 + ch2 * 16 + o2) * 5 + cc];
    bpart[((size_t)bq * R_ + (rbase + rr)) * C_ + c] = s;
  }
}

// b_new = (first ? 0 : b_prev) + (sum_bq bpart)/256; cvec = softmax over r per c.
__global__ __launch_bounds__(256) void k_bc(const float* __restrict__ bpart,
                                            float* __restrict__ bvec,
                                            float* __restrict__ cvec, int first) {
  const int c = blockIdx.x;
  const int t = threadIdx.x;
  __shared__ float smx[4];
  __shared__ float sms[4];
  float bv[5], ef[5];
  float mx = -3.402823466e38f;
#pragma unroll
  for (int k = 0; k < 5; ++k) {
    int r = t + k * 256;
    if (r < R_) {
      float s = bpart[(size_t)r * C_ + c]
              + bpart[((size_t)R_ + r) * C_ + c]
              + bpart[((size_t)2 * R_ + r) * C_ + c]
              + bpart[((size_t)3 * R_ + r) * C_ + c];
      float val = s * (1.0f / 256.0f);
      if (!first) val += bvec[r * C_ + c];
      bvec[r * C_ + c] = val;
      bv[k] = val;
      mx = fmaxf(mx, val);
    }
  }
  mx = fmaxf(mx, __shfl_xor(mx, 1));  mx = fmaxf(mx, __shfl_xor(mx, 2));
  mx = fmaxf(mx, __shfl_xor(mx, 4));  mx = fmaxf(mx, __shfl_xor(mx, 8));
  mx = fmaxf(mx, __shfl_xor(mx, 16)); mx = fmaxf(mx, __shfl_xor(mx, 32));
  if ((t & 63) == 0) smx[t >> 6] = mx;
  __syncthreads();
  const float MX = fmaxf(fmaxf(smx[0], smx[1]), fmaxf(smx[2], smx[3]));
  float se = 0.0f;
#pragma unroll
  for (int k = 0; k < 5; ++k) {
    int r = t + k * 256;
    if (r < R_) { ef[k] = expf(bv[k] - MX); se += ef[k]; }
  }
  se += __shfl_xor(se, 1);  se += __shfl_xor(se, 2);  se += __shfl_xor(se, 4);
  se += __shfl_xor(se, 8);  se += __shfl_xor(se, 16); se += __shfl_xor(se, 32);
  if ((t & 63) == 0) sms[t >> 6] = se;
  __syncthreads();
  const float inv = 1.0f / ((sms[0] + sms[1]) + (sms[2] + sms[3]));
#pragma unroll
  for (int k = 0; k < 5; ++k) {
    int r = t + k * 256;
    if (r < R_) cvec[r * C_ + c] = ef[k] * inv;
  }
}

extern "C" void kernel_launch(void* const* d_in, const int* in_sizes, int n_in,
                              void* d_out, int out_size, void* d_ws, size_t ws_size,
                              hipStream_t stream) {
  const float* x = (const float*)d_in[0];  // (B,R,I) fp32
  const float* W = (const float*)d_in[1];  // (R,C,O,I) fp32
  float* out = (float*)d_out;              // (B,C,O,1) fp32
  float* ws = (float*)d_ws;

  float* partial = ws;                             // 128 * NV
  float* v     = partial + (size_t)KS_NSEG * NV;   // NV, layout [co][b]
  float* bvec  = v + NV;
  float* cvec  = bvec + (R_ * C_);
  float* bpart = cvec + (R_ * C_);                 // 4 * R * C

  for (int it = 0; it < 3; ++it) {
    k_s<<<KS_NSEG * 4, 256, 0, stream>>>(x, W, cvec, partial, it > 0 ? 1 : 0);
    k_sv<<<NV / 256, 256, 0, stream>>>(partial, (it == 2) ? out : v, it == 2 ? 1 : 0);
    if (it < 2) {
      k_a<<<KA_NSEG * 4, 256, 0, stream>>>(x, W, v, bpart);
      k_bc<<<C_, 256, 0, stream>>>(bpart, bvec, cvec, it == 0 ? 1 : 0);
    }
  }
}